// Round 1
// baseline (241.651 us; speedup 1.0000x reference)
//
#include <hip/hip_runtime.h>
#include <hip/hip_fp16.h>

#define B_ 128
#define T_ 512
#define VT_ 2048
#define E_ 1024
#define D_ 1024

typedef _Float16 h8 __attribute__((ext_vector_type(8)));
typedef float f4 __attribute__((ext_vector_type(4)));

#define C2LE 2.8853900817779268f  // 2*log2(e)
#define L2E  1.4426950408889634f

static __device__ __forceinline__ float rcpf(float x) { return __builtin_amdgcn_rcpf(x); }

// C[M,N] = scale * (A0@B0 (k<ksplit) + A1@B1 (k>=ksplit) + bias)
// A operands split hi/lo f16 (2 MFMA passes) to keep rounding noise ~2^-11 on B only.
__global__ __launch_bounds__(256) void gemm_f16_hilo(
    const float* __restrict__ A0, int lda0, const float* __restrict__ B0,
    const float* __restrict__ A1, int lda1, const float* __restrict__ B1,
    const float* __restrict__ bias, float* __restrict__ C,
    int N, int Ktot, int ksplit, float scale)
{
    __shared__ _Float16 Ah[64][40];  // pad 40 halves (80B row) -> conflict-free b128 reads
    __shared__ _Float16 Al[64][40];
    __shared__ _Float16 Bs[64][40];  // B stored transposed: [n][k]

    const int tid = threadIdx.x;
    const int m0 = blockIdx.x * 64;
    const int n0 = blockIdx.y * 64;

    const int wave = tid >> 6, lane = tid & 63;
    const int wm = (wave >> 1) * 32, wn = (wave & 1) * 32;
    const int r = lane & 15, g = lane >> 4;

    f4 acc[2][2] = {};

    const int ar = tid >> 2;         // A stage: row 0..63
    const int ak = (tid & 3) * 8;    // k offset 0,8,16,24
    const int bc = tid & 63;         // B stage: col 0..63
    const int bk = (tid >> 6) * 8;   // k offset 0,8,16,24

    for (int kk = 0; kk < Ktot; kk += 32) {
        const float* A; const float* Bp; int koff, lda;
        if (kk < ksplit) { A = A0; Bp = B0; koff = kk;          lda = lda0; }
        else             { A = A1; Bp = B1; koff = kk - ksplit; lda = lda1; }

        // stage A tile (64x32) as hi/lo f16
        {
            const float* src = A + (size_t)(m0 + ar) * lda + koff + ak;
            float v0[8];
            *(f4*)&v0[0] = *(const f4*)(src);
            *(f4*)&v0[4] = *(const f4*)(src + 4);
            h8 hi8, lo8;
            #pragma unroll
            for (int i = 0; i < 8; ++i) {
                _Float16 hi = (_Float16)v0[i];
                hi8[i] = hi;
                lo8[i] = (_Float16)(v0[i] - (float)hi);
            }
            *(h8*)&Ah[ar][ak] = hi8;
            *(h8*)&Al[ar][ak] = lo8;
        }
        // stage B tile (32x64) transposed into [col][k]
        {
            h8 t8;
            #pragma unroll
            for (int i = 0; i < 8; ++i)
                t8[i] = (_Float16)Bp[(size_t)(koff + bk + i) * N + n0 + bc];
            *(h8*)&Bs[bc][bk] = t8;
        }
        __syncthreads();

        h8 afh[2], afl[2], bf[2];
        #pragma unroll
        for (int i = 0; i < 2; ++i) {
            afh[i] = *(const h8*)&Ah[wm + i*16 + r][g*8];
            afl[i] = *(const h8*)&Al[wm + i*16 + r][g*8];
            bf[i]  = *(const h8*)&Bs[wn + i*16 + r][g*8];
        }
        #pragma unroll
        for (int i = 0; i < 2; ++i)
            #pragma unroll
            for (int j = 0; j < 2; ++j) {
                acc[i][j] = __builtin_amdgcn_mfma_f32_16x16x32_f16(afl[i], bf[j], acc[i][j], 0, 0, 0);
                acc[i][j] = __builtin_amdgcn_mfma_f32_16x16x32_f16(afh[i], bf[j], acc[i][j], 0, 0, 0);
            }
        __syncthreads();
    }

    // epilogue: C/D layout col=lane&15, row=(lane>>4)*4+reg  [m89-verified]
    #pragma unroll
    for (int i = 0; i < 2; ++i)
        #pragma unroll
        for (int j = 0; j < 2; ++j) {
            const int col = n0 + wn + j*16 + r;
            const float bv = bias ? bias[col] : 0.0f;
            #pragma unroll
            for (int q = 0; q < 4; ++q) {
                const int row = m0 + wm + i*16 + g*4 + q;
                C[(size_t)row * N + col] = scale * (acc[i][j][q] + bv);
            }
        }
}

// partial score: SP[bz][b][t] = sum_{d in chunk bz} v[d] * rcp(exp2(X[b,d]+Y[t,d]) + 1)
__global__ __launch_bounds__(256) void score_kernel(
    const float* __restrict__ X, const float* __restrict__ Y,
    const float* __restrict__ v, float* __restrict__ SP)
{
    __shared__ float Xs[16][132];  // stride 132: lane stride 4 banks -> ~2-way max
    __shared__ float Ys[64][132];
    __shared__ float vs[128];

    const int tid = threadIdx.x;
    const int b0 = blockIdx.x * 16;
    const int t0 = blockIdx.y * 64;
    const int d0 = blockIdx.z * 128;

    #pragma unroll
    for (int i = 0; i < 8; ++i) {
        int idx = tid + i * 256;
        int row = idx >> 5, c4 = idx & 31;
        *(f4*)&Ys[row][c4*4] = *(const f4*)&Y[(size_t)(t0 + row) * D_ + d0 + c4*4];
    }
    #pragma unroll
    for (int i = 0; i < 2; ++i) {
        int idx = tid + i * 256;
        int row = idx >> 5, c4 = idx & 31;
        *(f4*)&Xs[row][c4*4] = *(const f4*)&X[(size_t)(b0 + row) * D_ + d0 + c4*4];
    }
    if (tid < 32) *(f4*)&vs[tid*4] = *(const f4*)&v[d0 + tid*4];
    __syncthreads();

    const int tq = tid & 31, bq = tid >> 5;
    float a00 = 0.f, a01 = 0.f, a10 = 0.f, a11 = 0.f;

    for (int dd = 0; dd < 32; ++dd) {
        f4 xa = *(const f4*)&Xs[bq][dd*4];
        f4 xb = *(const f4*)&Xs[bq + 8][dd*4];
        f4 ya = *(const f4*)&Ys[tq][dd*4];
        f4 yb = *(const f4*)&Ys[tq + 32][dd*4];
        f4 vv = *(const f4*)&vs[dd*4];
        #pragma unroll
        for (int j = 0; j < 4; ++j) {
            float e;
            e = exp2f(xa[j] + ya[j]); a00 += vv[j] * rcpf(e + 1.0f);
            e = exp2f(xa[j] + yb[j]); a01 += vv[j] * rcpf(e + 1.0f);
            e = exp2f(xb[j] + ya[j]); a10 += vv[j] * rcpf(e + 1.0f);
            e = exp2f(xb[j] + yb[j]); a11 += vv[j] * rcpf(e + 1.0f);
        }
    }

    float* sp = SP + (size_t)blockIdx.z * (B_ * T_);
    sp[(size_t)(b0 + bq)     * T_ + t0 + tq]      = a00;
    sp[(size_t)(b0 + bq)     * T_ + t0 + tq + 32] = a01;
    sp[(size_t)(b0 + bq + 8) * T_ + t0 + tq]      = a10;
    sp[(size_t)(b0 + bq + 8) * T_ + t0 + tq + 32] = a11;
}

// softmax over t of score = -2 * sum_z SP[z][b][t]  (the +sum(v) constant cancels)
__global__ __launch_bounds__(256) void softmax_kernel(
    const float* __restrict__ SP, float* __restrict__ out)
{
    const int b = blockIdx.x, tid = threadIdx.x;
    float s0 = 0.f, s1 = 0.f;
    #pragma unroll
    for (int z = 0; z < 8; ++z) {
        s0 += SP[(size_t)z * B_ * T_ + (size_t)b * T_ + tid];
        s1 += SP[(size_t)z * B_ * T_ + (size_t)b * T_ + tid + 256];
    }
    s0 *= -2.0f; s1 *= -2.0f;

    float m = fmaxf(s0, s1);
    #pragma unroll
    for (int off = 32; off >= 1; off >>= 1) m = fmaxf(m, __shfl_xor(m, off));
    __shared__ float red[4];
    __shared__ float red2[4];
    const int wv = tid >> 6;
    if ((tid & 63) == 0) red[wv] = m;
    __syncthreads();
    m = fmaxf(fmaxf(red[0], red[1]), fmaxf(red[2], red[3]));

    float e0 = exp2f((s0 - m) * L2E);
    float e1 = exp2f((s1 - m) * L2E);
    float sum = e0 + e1;
    #pragma unroll
    for (int off = 32; off >= 1; off >>= 1) sum += __shfl_xor(sum, off);
    if ((tid & 63) == 0) red2[wv] = sum;
    __syncthreads();
    sum = red2[0] + red2[1] + red2[2] + red2[3];

    const float rs = rcpf(sum);
    out[(size_t)b * T_ + tid]       = e0 * rs;
    out[(size_t)b * T_ + tid + 256] = e1 * rs;
}

extern "C" void kernel_launch(void* const* d_in, const int* in_sizes, int n_in,
                              void* d_out, int out_size, void* d_ws, size_t ws_size,
                              hipStream_t stream)
{
    const float* hidden = (const float*)d_in[0];
    const float* topic  = (const float*)d_in[1];
    const float* enc    = (const float*)d_in[2];
    const float* W_h    = (const float*)d_in[3];
    const float* W_t    = (const float*)d_in[4];
    const float* W_e    = (const float*)d_in[5];
    const float* bvec   = (const float*)d_in[6];
    const float* vvec   = (const float*)d_in[7];
    float* out = (float*)d_out;

    float* Xb = (float*)d_ws;       // [128][1024]
    float* Yb = Xb + B_ * D_;       // [512][1024]
    float* SP = Yb + T_ * D_;       // [8][128][512]

    // X = c*(hidden@W_h + enc@W_e + bias)
    gemm_f16_hilo<<<dim3(2, 16), 256, 0, stream>>>(
        hidden, D_, W_h, enc, E_, W_e, bvec, Xb, D_, D_ + E_, D_, C2LE);
    // Y = c*(topic@W_t)
    gemm_f16_hilo<<<dim3(8, 16), 256, 0, stream>>>(
        topic, VT_, W_t, topic, VT_, W_t, nullptr, Yb, D_, VT_, VT_, C2LE);
    // partial scores over 8 d-chunks
    score_kernel<<<dim3(8, 8, 8), 256, 0, stream>>>(Xb, Yb, vvec, SP);
    // row softmax
    softmax_kernel<<<128, 256, 0, stream>>>(SP, out);
}

// Round 2
// 119.608 us; speedup vs baseline: 2.0204x; 2.0204x over previous
//
#include <hip/hip_runtime.h>
#include <hip/hip_fp16.h>

#define B_ 128
#define T_ 512
#define VT_ 2048
#define E_ 1024
#define D_ 1024

typedef _Float16 h8 __attribute__((ext_vector_type(8)));
typedef float f4 __attribute__((ext_vector_type(4)));

#define C2LE 2.8853900817779268f  // 2*log2(e)
#define L2E  1.4426950408889634f

static __device__ __forceinline__ float rcpf(float x) { return __builtin_amdgcn_rcpf(x); }
static __device__ __forceinline__ float ex2(float x)  { return __builtin_amdgcn_exp2f(x); }

// ---------------- workspace layout ----------------
// P     : float[4][640][1024]   split-K partials (rows 0-127 = X, 128-639 = Y)
// SP    : float[8][128][512]    per-d-chunk score partials
// packA : f16[640*2048]         A fragments, KB=64  (rows: hidden|enc then topic)
// packB : f16[1M + 1M + 2M]     W_h^T, W_e^T, W_t^T fragments
#define P_FLOATS   (4 * 640 * 1024)
#define SP_FLOATS  (8 * 128 * 512)
#define PA_HALVES  (640 * 2048)
#define PB_WH      0
#define PB_WE      1048576
#define PB_WT      2097152

// pack A source [M][ld] fp32 -> f16 fragment order; dst frag (mb_off+mb, kb_off+kb), KB_dst=64
__device__ __forceinline__ void packA_do(const float* __restrict__ src, int ld, int KBs,
                                         _Float16* __restrict__ dst, int mb_off, int kb_off, int t)
{
    const int lane = t & 63;
    const int fb = t >> 6;
    const int kb = fb % KBs, mb = fb / KBs;
    const int r = lane & 15, g = lane >> 4;
    const float* s = src + (size_t)(mb * 16 + r) * ld + kb * 32 + g * 8;
    f4 v0 = *(const f4*)s, v1 = *(const f4*)(s + 4);
    h8 h;
    h[0] = (_Float16)v0[0]; h[1] = (_Float16)v0[1]; h[2] = (_Float16)v0[2]; h[3] = (_Float16)v0[3];
    h[4] = (_Float16)v1[0]; h[5] = (_Float16)v1[1]; h[6] = (_Float16)v1[2]; h[7] = (_Float16)v1[3];
    *(h8*)(dst + ((size_t)((mb_off + mb) * 64 + (kb_off + kb)) * 64 + lane) * 8) = h;
}

// pack W [K][1024] fp32 -> B^T f16 fragment order (lane holds col n=lane&15, k=(lane>>4)*8+j)
__device__ __forceinline__ void packB_do(const float* __restrict__ W, int KB,
                                         _Float16* __restrict__ dst, int t)
{
    const int lane = t & 63;
    const int fb = t >> 6;
    const int kb = fb % KB, nb = fb / KB;
    const int r = lane & 15, g = lane >> 4;
    const float* s = W + (size_t)(kb * 32 + g * 8) * 1024 + nb * 16 + r;
    h8 h;
    #pragma unroll
    for (int j = 0; j < 8; ++j) h[j] = (_Float16)s[(size_t)j * 1024];
    *(h8*)(dst + ((size_t)(nb * KB + kb) * 64 + lane) * 8) = h;
}

__global__ __launch_bounds__(256) void pack_kernel(
    const float* __restrict__ hidden, const float* __restrict__ topic,
    const float* __restrict__ enc,
    const float* __restrict__ W_h, const float* __restrict__ W_t, const float* __restrict__ W_e,
    _Float16* __restrict__ pA, _Float16* __restrict__ pB)
{
    const int bid = blockIdx.x, tid = threadIdx.x;
    if      (bid <   64) packA_do(hidden, 1024, 32, pA, 0,  0, bid * 256 + tid);
    else if (bid <  128) packA_do(enc,    1024, 32, pA, 0, 32, (bid -  64) * 256 + tid);
    else if (bid <  640) packA_do(topic,  2048, 64, pA, 8,  0, (bid - 128) * 256 + tid);
    else if (bid < 1152) packB_do(W_h, 32, pB + PB_WH, (bid -  640) * 256 + tid);
    else if (bid < 1664) packB_do(W_e, 32, pB + PB_WE, (bid - 1152) * 256 + tid);
    else                 packB_do(W_t, 64, pB + PB_WT, (bid - 1664) * 256 + tid);
}

// fused GEMM: out rows 0-127: [hidden|enc]@[W_h;W_e]; rows 128-639: topic@W_t
// no LDS: fragments pre-packed, direct global->VGPR loads. split-K=4 partials.
__global__ __launch_bounds__(256) void gemm_kernel(const _Float16* __restrict__ pA,
                                                   const _Float16* __restrict__ pB,
                                                   float* __restrict__ P)
{
    const int mt = blockIdx.x, nt = blockIdx.y, s = blockIdx.z;
    const int tid = threadIdx.x, wave = tid >> 6, lane = tid & 63;
    const int wm = (wave >> 1) * 32, wn = (wave & 1) * 32;
    const int r = lane & 15, g = lane >> 4;

    const int kb0 = s * 16;
    const int mb0 = (mt * 64 + wm) >> 4;
    const int nb0 = (nt * 64 + wn) >> 4;

    const _Float16* Bp; int KB_B, kbB;
    if (mt < 2) {
        if (kb0 < 32) { Bp = pB + PB_WH; kbB = kb0; }
        else          { Bp = pB + PB_WE; kbB = kb0 - 32; }
        KB_B = 32;
    } else {
        Bp = pB + PB_WT; kbB = kb0; KB_B = 64;
    }

    const _Float16* Ap = pA + ((size_t)(mb0 * 64 + kb0) * 64 + lane) * 8;
    const _Float16* Bq = Bp + ((size_t)(nb0 * KB_B + kbB) * 64 + lane) * 8;
    const size_t aStrI = (size_t)64 * 512;     // mb -> mb+1
    const size_t bStrJ = (size_t)KB_B * 512;   // nb -> nb+1

    f4 acc00{}, acc01{}, acc10{}, acc11{};
    #pragma unroll 4
    for (int ks = 0; ks < 16; ++ks) {
        h8 a0 = *(const h8*)(Ap);
        h8 a1 = *(const h8*)(Ap + aStrI);
        h8 b0 = *(const h8*)(Bq);
        h8 b1 = *(const h8*)(Bq + bStrJ);
        acc00 = __builtin_amdgcn_mfma_f32_16x16x32_f16(a0, b0, acc00, 0, 0, 0);
        acc01 = __builtin_amdgcn_mfma_f32_16x16x32_f16(a0, b1, acc01, 0, 0, 0);
        acc10 = __builtin_amdgcn_mfma_f32_16x16x32_f16(a1, b0, acc10, 0, 0, 0);
        acc11 = __builtin_amdgcn_mfma_f32_16x16x32_f16(a1, b1, acc11, 0, 0, 0);
        Ap += 512; Bq += 512;
    }

    // C/D layout: col = lane&15, row = (lane>>4)*4 + q
    float* Pp = P + ((size_t)s * 640 + mt * 64 + wm + g * 4) * 1024 + nt * 64 + wn + r;
    #pragma unroll
    for (int q = 0; q < 4; ++q) {
        Pp[(size_t)q * 1024 +  0]        = C2LE * acc00[q];
        Pp[(size_t)q * 1024 + 16]        = C2LE * acc01[q];
        Pp[(size_t)(16 + q) * 1024 +  0] = C2LE * acc10[q];
        Pp[(size_t)(16 + q) * 1024 + 16] = C2LE * acc11[q];
    }
}

// SP[z][b][t] = sum_{d in chunk z} v_d * rcp(exp2(X+Y) + 1); merges the 4 split-K partials.
__global__ __launch_bounds__(256) void score_kernel(const float* __restrict__ P,
                                                    const float* __restrict__ bias,
                                                    const float* __restrict__ v,
                                                    float* __restrict__ SP)
{
    __shared__ float Xs[16][128];   // stride 128 + XOR-16 swizzle on 16B units
    __shared__ float Ys[64][128];
    __shared__ float vs[128];

    const int tid = threadIdx.x;
    const int b0 = blockIdx.x * 16;
    const int t0 = blockIdx.y * 64;
    const int d0 = blockIdx.z * 128;
    const size_t PS = (size_t)640 * 1024;

    #pragma unroll
    for (int i = 0; i < 8; ++i) {
        int idx = tid + i * 256;
        int row = idx >> 5, c4 = idx & 31;
        size_t off = (size_t)(128 + t0 + row) * 1024 + d0 + c4 * 4;
        f4 vv = *(const f4*)&P[off];
        vv += *(const f4*)&P[off + PS];
        vv += *(const f4*)&P[off + 2 * PS];
        vv += *(const f4*)&P[off + 3 * PS];
        *(f4*)&Ys[row][(c4 ^ (row & 15)) * 4] = vv;
    }
    #pragma unroll
    for (int i = 0; i < 2; ++i) {
        int idx = tid + i * 256;
        int row = idx >> 5, c4 = idx & 31;
        size_t off = (size_t)(b0 + row) * 1024 + d0 + c4 * 4;
        f4 vv = *(const f4*)&P[off];
        vv += *(const f4*)&P[off + PS];
        vv += *(const f4*)&P[off + 2 * PS];
        vv += *(const f4*)&P[off + 3 * PS];
        f4 bb = *(const f4*)&bias[d0 + c4 * 4];
        vv += bb * C2LE;
        *(f4*)&Xs[row][(c4 ^ (row & 15)) * 4] = vv;
    }
    if (tid < 32) *(f4*)&vs[tid * 4] = *(const f4*)&v[d0 + tid * 4];
    __syncthreads();

    const int tq = tid & 31, bq = tid >> 5;
    const int sx0 = bq & 15, sx1 = (bq + 8) & 15, sy = tq & 15;
    float a00 = 0.f, a01 = 0.f, a10 = 0.f, a11 = 0.f;

    for (int dd = 0; dd < 32; ++dd) {
        f4 xa = *(const f4*)&Xs[bq]     [(dd ^ sx0) * 4];
        f4 xb = *(const f4*)&Xs[bq + 8] [(dd ^ sx1) * 4];
        f4 ya = *(const f4*)&Ys[tq]     [(dd ^ sy) * 4];
        f4 yb = *(const f4*)&Ys[tq + 32][(dd ^ sy) * 4];
        f4 vv = *(const f4*)&vs[dd * 4];
        #pragma unroll
        for (int j = 0; j < 4; ++j) {
            float e;
            e = ex2(xa[j] + ya[j]); a00 += vv[j] * rcpf(e + 1.0f);
            e = ex2(xa[j] + yb[j]); a01 += vv[j] * rcpf(e + 1.0f);
            e = ex2(xb[j] + ya[j]); a10 += vv[j] * rcpf(e + 1.0f);
            e = ex2(xb[j] + yb[j]); a11 += vv[j] * rcpf(e + 1.0f);
        }
    }

    float* sp = SP + (size_t)blockIdx.z * (B_ * T_);
    sp[(size_t)(b0 + bq)     * T_ + t0 + tq]      = a00;
    sp[(size_t)(b0 + bq)     * T_ + t0 + tq + 32] = a01;
    sp[(size_t)(b0 + bq + 8) * T_ + t0 + tq]      = a10;
    sp[(size_t)(b0 + bq + 8) * T_ + t0 + tq + 32] = a11;
}

// softmax over t of score = -2 * sum_z SP[z][b][t]  (constant sum(v) cancels)
__global__ __launch_bounds__(256) void softmax_kernel(
    const float* __restrict__ SP, float* __restrict__ out)
{
    const int b = blockIdx.x, tid = threadIdx.x;
    float s0 = 0.f, s1 = 0.f;
    #pragma unroll
    for (int z = 0; z < 8; ++z) {
        s0 += SP[(size_t)z * B_ * T_ + (size_t)b * T_ + tid];
        s1 += SP[(size_t)z * B_ * T_ + (size_t)b * T_ + tid + 256];
    }
    s0 *= -2.0f; s1 *= -2.0f;

    float m = fmaxf(s0, s1);
    #pragma unroll
    for (int off = 32; off >= 1; off >>= 1) m = fmaxf(m, __shfl_xor(m, off));
    __shared__ float red[4];
    __shared__ float red2[4];
    const int wv = tid >> 6;
    if ((tid & 63) == 0) red[wv] = m;
    __syncthreads();
    m = fmaxf(fmaxf(red[0], red[1]), fmaxf(red[2], red[3]));

    float e0 = ex2((s0 - m) * L2E);
    float e1 = ex2((s1 - m) * L2E);
    float sum = e0 + e1;
    #pragma unroll
    for (int off = 32; off >= 1; off >>= 1) sum += __shfl_xor(sum, off);
    if ((tid & 63) == 0) red2[wv] = sum;
    __syncthreads();
    sum = red2[0] + red2[1] + red2[2] + red2[3];

    const float rs = rcpf(sum);
    out[(size_t)b * T_ + tid]       = e0 * rs;
    out[(size_t)b * T_ + tid + 256] = e1 * rs;
}

extern "C" void kernel_launch(void* const* d_in, const int* in_sizes, int n_in,
                              void* d_out, int out_size, void* d_ws, size_t ws_size,
                              hipStream_t stream)
{
    const float* hidden = (const float*)d_in[0];
    const float* topic  = (const float*)d_in[1];
    const float* enc    = (const float*)d_in[2];
    const float* W_h    = (const float*)d_in[3];
    const float* W_t    = (const float*)d_in[4];
    const float* W_e    = (const float*)d_in[5];
    const float* bvec   = (const float*)d_in[6];
    const float* vvec   = (const float*)d_in[7];
    float* out = (float*)d_out;

    float* P      = (float*)d_ws;
    float* SPb    = P + P_FLOATS;
    _Float16* pA  = (_Float16*)(SPb + SP_FLOATS);
    _Float16* pB  = pA + PA_HALVES;

    pack_kernel<<<2688, 256, 0, stream>>>(hidden, topic, enc, W_h, W_t, W_e, pA, pB);
    gemm_kernel<<<dim3(10, 16, 4), 256, 0, stream>>>(pA, pB, P);
    score_kernel<<<dim3(8, 8, 8), 256, 0, stream>>>(P, bvec, vvec, SPb);
    softmax_kernel<<<128, 256, 0, stream>>>(SPb, out);
}

// Round 4
// 115.020 us; speedup vs baseline: 2.1010x; 1.0399x over previous
//
#include <hip/hip_runtime.h>
#include <hip/hip_fp16.h>

#define B_ 128
#define T_ 512
#define VT_ 2048
#define E_ 1024
#define D_ 1024

typedef _Float16 h8 __attribute__((ext_vector_type(8)));
typedef float f4 __attribute__((ext_vector_type(4)));

#define C2LE 2.8853900817779268f  // 2*log2(e)
#define L2E  1.4426950408889634f

static __device__ __forceinline__ float rcpf(float x) { return __builtin_amdgcn_rcpf(x); }
static __device__ __forceinline__ float ex2(float x)  { return __builtin_amdgcn_exp2f(x); }

// ---------------- workspace layout (floats / halves) ----------------
// P  : float[8][640][1024]  split-K partials (rows 0-127 = X, 128-639 = Y)
// R  : float[640][1024]     reduced partials (+ C2LE*bias on X rows)
// SP : float[8][128][512]   per-d-chunk score partials
// pA : f16[640*2048]        A fragments (KB=64)
// pB : f16[1M + 1M + 2M]    W_h^T, W_e^T, W_t^T fragments
#define P_FLOATS   (8 * 640 * 1024)
#define R_FLOATS   (640 * 1024)
#define SP_FLOATS  (8 * 128 * 512)
#define PA_HALVES  (640 * 2048)
#define PB_WH      0
#define PB_WE      1048576
#define PB_WT      2097152

// pack A source [M][ld] fp32 -> f16 fragment order; frag (mb_off+mb, kb_off+kb), KB_dst=64
__device__ __forceinline__ void packA_do(const float* __restrict__ src, int ld, int KBs,
                                         _Float16* __restrict__ dst, int mb_off, int kb_off, int t)
{
    const int lane = t & 63;
    const int fb = t >> 6;
    const int kb = fb % KBs, mb = fb / KBs;
    const int r = lane & 15, g = lane >> 4;
    const float* s = src + (size_t)(mb * 16 + r) * ld + kb * 32 + g * 8;
    f4 v0 = *(const f4*)s, v1 = *(const f4*)(s + 4);
    h8 h;
    h[0] = (_Float16)v0[0]; h[1] = (_Float16)v0[1]; h[2] = (_Float16)v0[2]; h[3] = (_Float16)v0[3];
    h[4] = (_Float16)v1[0]; h[5] = (_Float16)v1[1]; h[6] = (_Float16)v1[2]; h[7] = (_Float16)v1[3];
    *(h8*)(dst + ((size_t)((mb_off + mb) * 64 + (kb_off + kb)) * 64 + lane) * 8) = h;
}

// pack W [K][1024] fp32 -> B^T f16 fragment order (lane: col n=lane&15, k=(lane>>4)*8+j)
__device__ __forceinline__ void packB_do(const float* __restrict__ W, int KB,
                                         _Float16* __restrict__ dst, int t)
{
    const int lane = t & 63;
    const int fb = t >> 6;
    const int kb = fb % KB, nb = fb / KB;
    const int r = lane & 15, g = lane >> 4;
    const float* s = W + (size_t)(kb * 32 + g * 8) * 1024 + nb * 16 + r;
    h8 h;
    #pragma unroll
    for (int j = 0; j < 8; ++j) h[j] = (_Float16)s[(size_t)j * 1024];
    *(h8*)(dst + ((size_t)(nb * KB + kb) * 64 + lane) * 8) = h;
}

__global__ __launch_bounds__(256) void pack_kernel(
    const float* __restrict__ hidden, const float* __restrict__ topic,
    const float* __restrict__ enc,
    const float* __restrict__ W_h, const float* __restrict__ W_t, const float* __restrict__ W_e,
    _Float16* __restrict__ pA, _Float16* __restrict__ pB)
{
    const int bid = blockIdx.x, tid = threadIdx.x;
    if      (bid <   64) packA_do(hidden, 1024, 32, pA, 0,  0, bid * 256 + tid);
    else if (bid <  128) packA_do(enc,    1024, 32, pA, 0, 32, (bid -  64) * 256 + tid);
    else if (bid <  640) packA_do(topic,  2048, 64, pA, 8,  0, (bid - 128) * 256 + tid);
    else if (bid < 1152) packB_do(W_h, 32, pB + PB_WH, (bid -  640) * 256 + tid);
    else if (bid < 1664) packB_do(W_e, 32, pB + PB_WE, (bid - 1152) * 256 + tid);
    else                 packB_do(W_t, 64, pB + PB_WT, (bid - 1664) * 256 + tid);
}

// fused GEMM, split-K=8, wave tile 32x64 (acc 2x4), XCD-swizzled so each XCD
// owns one K-slice s (A 327KB + B 512KB fits its private L2).
__global__ __launch_bounds__(256, 3) void gemm_kernel(const _Float16* __restrict__ pA,
                                                      const _Float16* __restrict__ pB,
                                                      float* __restrict__ P)
{
    // bijective XCD swizzle: nwg=640, chunk 80 = full (mt,nt) plane for one s
    const int lin = blockIdx.x;
    const int sw  = (lin & 7) * 80 + (lin >> 3);
    const int s   = sw / 80;
    const int rem = sw % 80;
    const int mt  = rem % 10;
    const int nt  = rem / 10;

    const int tid = threadIdx.x, wave = tid >> 6, lane = tid & 63;
    const int wm = (wave >> 1) * 32;   // 0 or 32
    const int wn = (wave & 1) * 64;    // 0 or 64
    const int r = lane & 15, g = lane >> 4;

    const int mb0 = mt * 4 + (wm >> 4);
    const int nb0 = (nt * 128 + wn) >> 4;
    const int kb0 = s * 8;

    const _Float16* Bp; int KB_B, kbB0;
    if (mt < 2) {  // X rows: s<4 -> W_h slice, s>=4 -> W_e slice (no mid-loop switch)
        if (kb0 < 32) { Bp = pB + PB_WH; kbB0 = kb0; }
        else          { Bp = pB + PB_WE; kbB0 = kb0 - 32; }
        KB_B = 32;
    } else { Bp = pB + PB_WT; kbB0 = kb0; KB_B = 64; }

    const _Float16* Ap = pA + ((size_t)(mb0 * 64 + kb0) * 64 + lane) * 8;
    const _Float16* Bq = Bp + ((size_t)(nb0 * KB_B + kbB0) * 64 + lane) * 8;
    const size_t aStrM = (size_t)64 * 512;        // mb -> mb+1
    const size_t bStrN = (size_t)KB_B * 512;      // nb -> nb+1

    f4 acc[2][4] = {};
    #pragma unroll
    for (int ks = 0; ks < 8; ++ks) {
        h8 a0 = *(const h8*)(Ap + (size_t)ks * 512);
        h8 a1 = *(const h8*)(Ap + aStrM + (size_t)ks * 512);
        h8 b0 = *(const h8*)(Bq + (size_t)ks * 512);
        h8 b1 = *(const h8*)(Bq + bStrN + (size_t)ks * 512);
        h8 b2 = *(const h8*)(Bq + 2 * bStrN + (size_t)ks * 512);
        h8 b3 = *(const h8*)(Bq + 3 * bStrN + (size_t)ks * 512);
        acc[0][0] = __builtin_amdgcn_mfma_f32_16x16x32_f16(a0, b0, acc[0][0], 0, 0, 0);
        acc[0][1] = __builtin_amdgcn_mfma_f32_16x16x32_f16(a0, b1, acc[0][1], 0, 0, 0);
        acc[0][2] = __builtin_amdgcn_mfma_f32_16x16x32_f16(a0, b2, acc[0][2], 0, 0, 0);
        acc[0][3] = __builtin_amdgcn_mfma_f32_16x16x32_f16(a0, b3, acc[0][3], 0, 0, 0);
        acc[1][0] = __builtin_amdgcn_mfma_f32_16x16x32_f16(a1, b0, acc[1][0], 0, 0, 0);
        acc[1][1] = __builtin_amdgcn_mfma_f32_16x16x32_f16(a1, b1, acc[1][1], 0, 0, 0);
        acc[1][2] = __builtin_amdgcn_mfma_f32_16x16x32_f16(a1, b2, acc[1][2], 0, 0, 0);
        acc[1][3] = __builtin_amdgcn_mfma_f32_16x16x32_f16(a1, b3, acc[1][3], 0, 0, 0);
    }

    // C/D layout: col = lane&15, row = (lane>>4)*4 + q
    float* Pp = P + ((size_t)s * 640 + mt * 64 + wm + g * 4) * 1024 + nt * 128 + wn + r;
    #pragma unroll
    for (int i = 0; i < 2; ++i)
        #pragma unroll
        for (int j = 0; j < 4; ++j)
            #pragma unroll
            for (int q = 0; q < 4; ++q)
                Pp[(size_t)(i * 16 + q) * 1024 + j * 16] = C2LE * acc[i][j][q];
}

// R[row][d] = sum_z P[z][row][d] + (row<128 ? C2LE*bias[d] : 0)
__global__ __launch_bounds__(256) void reduce_kernel(const float* __restrict__ P,
                                                     const float* __restrict__ bias,
                                                     float* __restrict__ R)
{
    const int row = blockIdx.x, tid = threadIdx.x;
    const size_t off = (size_t)row * 1024 + tid * 4;
    const size_t PS = (size_t)640 * 1024;
    f4 acc = *(const f4*)&P[off];
    #pragma unroll
    for (int z = 1; z < 8; ++z) acc += *(const f4*)&P[off + (size_t)z * PS];
    if (row < 128) {
        f4 bb = *(const f4*)&bias[tid * 4];
        acc += bb * C2LE;
    }
    *(f4*)&R[off] = acc;
}

// SP[z][b][t] = sum_{d in chunk z} v_d * rcp(exp2(X+Y) + 1)
__global__ __launch_bounds__(256) void score_kernel(const float* __restrict__ R,
                                                    const float* __restrict__ v,
                                                    float* __restrict__ SP)
{
    __shared__ float Xs[16][128];   // XOR-16 swizzle on 16B units
    __shared__ float Ys[64][128];
    __shared__ float vs[128];

    const int tid = threadIdx.x;
    const int b0 = blockIdx.x * 16;
    const int t0 = blockIdx.y * 64;
    const int d0 = blockIdx.z * 128;

    #pragma unroll
    for (int i = 0; i < 8; ++i) {
        int idx = tid + i * 256;
        int row = idx >> 5, c4 = idx & 31;
        f4 vv = *(const f4*)&R[(size_t)(128 + t0 + row) * 1024 + d0 + c4 * 4];
        *(f4*)&Ys[row][(c4 ^ (row & 15)) * 4] = vv;
    }
    #pragma unroll
    for (int i = 0; i < 2; ++i) {
        int idx = tid + i * 256;
        int row = idx >> 5, c4 = idx & 31;
        f4 vv = *(const f4*)&R[(size_t)(b0 + row) * 1024 + d0 + c4 * 4];
        *(f4*)&Xs[row][(c4 ^ (row & 15)) * 4] = vv;
    }
    if (tid < 32) *(f4*)&vs[tid * 4] = *(const f4*)&v[d0 + tid * 4];
    __syncthreads();

    const int tq = tid & 31, bq = tid >> 5;
    const int sx0 = bq & 15, sx1 = (bq + 8) & 15, sy = tq & 15;
    float a00 = 0.f, a01 = 0.f, a10 = 0.f, a11 = 0.f;

    for (int dd = 0; dd < 32; ++dd) {
        f4 xa = *(const f4*)&Xs[bq]     [(dd ^ sx0) * 4];
        f4 xb = *(const f4*)&Xs[bq + 8] [(dd ^ sx1) * 4];
        f4 ya = *(const f4*)&Ys[tq]     [(dd ^ sy) * 4];
        f4 yb = *(const f4*)&Ys[tq + 32][(dd ^ sy) * 4];
        f4 vv = *(const f4*)&vs[dd * 4];
        #pragma unroll
        for (int j = 0; j < 4; ++j) {
            float e;
            e = ex2(xa[j] + ya[j]); a00 += vv[j] * rcpf(e + 1.0f);
            e = ex2(xa[j] + yb[j]); a01 += vv[j] * rcpf(e + 1.0f);
            e = ex2(xb[j] + ya[j]); a10 += vv[j] * rcpf(e + 1.0f);
            e = ex2(xb[j] + yb[j]); a11 += vv[j] * rcpf(e + 1.0f);
        }
    }

    float* sp = SP + (size_t)blockIdx.z * (B_ * T_);
    sp[(size_t)(b0 + bq)     * T_ + t0 + tq]      = a00;
    sp[(size_t)(b0 + bq)     * T_ + t0 + tq + 32] = a01;
    sp[(size_t)(b0 + bq + 8) * T_ + t0 + tq]      = a10;
    sp[(size_t)(b0 + bq + 8) * T_ + t0 + tq + 32] = a11;
}

// softmax over t of score = -2 * sum_z SP[z][b][t]  (constant sum(v) cancels)
__global__ __launch_bounds__(256) void softmax_kernel(
    const float* __restrict__ SP, float* __restrict__ out)
{
    const int b = blockIdx.x, tid = threadIdx.x;
    float s0 = 0.f, s1 = 0.f;
    #pragma unroll
    for (int z = 0; z < 8; ++z) {
        s0 += SP[(size_t)z * B_ * T_ + (size_t)b * T_ + tid];
        s1 += SP[(size_t)z * B_ * T_ + (size_t)b * T_ + tid + 256];
    }
    s0 *= -2.0f; s1 *= -2.0f;

    float m = fmaxf(s0, s1);
    #pragma unroll
    for (int off = 32; off >= 1; off >>= 1) m = fmaxf(m, __shfl_xor(m, off));
    __shared__ float red[4];
    __shared__ float red2[4];
    const int wv = tid >> 6;
    if ((tid & 63) == 0) red[wv] = m;
    __syncthreads();
    m = fmaxf(fmaxf(red[0], red[1]), fmaxf(red[2], red[3]));

    float e0 = ex2((s0 - m) * L2E);
    float e1 = ex2((s1 - m) * L2E);
    float sum = e0 + e1;
    #pragma unroll
    for (int off = 32; off >= 1; off >>= 1) sum += __shfl_xor(sum, off);
    if ((tid & 63) == 0) red2[wv] = sum;
    __syncthreads();
    sum = red2[0] + red2[1] + red2[2] + red2[3];

    const float rs = rcpf(sum);
    out[(size_t)b * T_ + tid]       = e0 * rs;
    out[(size_t)b * T_ + tid + 256] = e1 * rs;
}

extern "C" void kernel_launch(void* const* d_in, const int* in_sizes, int n_in,
                              void* d_out, int out_size, void* d_ws, size_t ws_size,
                              hipStream_t stream)
{
    const float* hidden = (const float*)d_in[0];
    const float* topic  = (const float*)d_in[1];
    const float* enc    = (const float*)d_in[2];
    const float* W_h    = (const float*)d_in[3];
    const float* W_t    = (const float*)d_in[4];
    const float* W_e    = (const float*)d_in[5];
    const float* bvec   = (const float*)d_in[6];
    const float* vvec   = (const float*)d_in[7];
    float* out = (float*)d_out;

    float* P      = (float*)d_ws;
    float* R      = P + P_FLOATS;
    float* SPb    = R + R_FLOATS;
    _Float16* pA  = (_Float16*)(SPb + SP_FLOATS);
    _Float16* pB  = pA + PA_HALVES;

    pack_kernel<<<2688, 256, 0, stream>>>(hidden, topic, enc, W_h, W_t, W_e, pA, pB);
    gemm_kernel<<<640, 256, 0, stream>>>(pA, pB, P);
    reduce_kernel<<<640, 256, 0, stream>>>(P, bvec, R);
    score_kernel<<<dim3(8, 8, 8), 256, 0, stream>>>(R, vvec, SPb);
    softmax_kernel<<<128, 256, 0, stream>>>(SPb, out);
}